// Round 1
// baseline (815.644 us; speedup 1.0000x reference)
//
#include <hip/hip_runtime.h>

#define DD 256
#define CC 104

// ---------------------------------------------------------------------------
// Kernel 1: per-edge prep — edge token gather + segment boundaries
// ---------------------------------------------------------------------------
__global__ void prep_kernel(const int* __restrict__ token_id,
                            const int* __restrict__ src_idx,
                            const int* __restrict__ dst_idx,
                            int* __restrict__ seg_start,
                            int* __restrict__ seg_end,
                            int* __restrict__ edge_tok,
                            int E)
{
    int e = blockIdx.x * blockDim.x + threadIdx.x;
    if (e >= E) return;
    int d = dst_idx[e];
    edge_tok[e] = token_id[src_idx[e]];
    if (e == 0 || dst_idx[e - 1] != d) seg_start[d] = e;
    if (e == E - 1 || dst_idx[e + 1] != d) seg_end[d] = e + 1;
}

// ---------------------------------------------------------------------------
// Kernel 2: one wave per dst node; lane covers 4 consecutive floats (float4).
// child_sum[d] = sum of emb[edge_tok[i]] for i in [seg_start, seg_end-1)
// (the last edge's message is excluded — it is the RNN "current input").
// deg==1 segments produce zeros (loop doesn't execute).
// ---------------------------------------------------------------------------
__global__ void seg_sum_kernel(const float* __restrict__ emb,
                               const int* __restrict__ edge_tok,
                               const int* __restrict__ seg_start,
                               const int* __restrict__ seg_end,
                               float* __restrict__ child,
                               int n_dst)
{
    int w = (blockIdx.x * blockDim.x + threadIdx.x) >> 6;
    int lane = threadIdx.x & 63;
    if (w >= n_dst) return;
    int s = seg_start[w];
    int e = seg_end[w];
    float4 acc = make_float4(0.f, 0.f, 0.f, 0.f);
    for (int i = s; i < e - 1; ++i) {
        int tok = edge_tok[i];                      // wave-uniform -> s_load
        const float4* row = (const float4*)(emb + (size_t)tok * DD);
        float4 v = row[lane];
        acc.x += v.x; acc.y += v.y; acc.z += v.z; acc.w += v.w;
    }
    ((float4*)(child + (size_t)w * DD))[lane] = acc;
}

// ---------------------------------------------------------------------------
// Kernel 3: GEMM1 + RNN epilogue, in-place: ft overwrites child_sum.
//   tile: 64 rows x 256 cols (full N) per 256-thread block, K-tile = 16.
//   thread: ry = t/64 -> rows ry*16+i (i<16, wave-uniform ry),
//           cy = t%64 -> cols cy+64j (j<4).
//   A reads from LDS are wave-broadcast (free); B reads are 2-way (free).
//   Epilogue: v = relu(acc + b[c]); ft = last_msg + (deg>1 ? v : 0)
//   where last_msg[m] = emb[edge_tok[seg_end[m]-1]].
// ---------------------------------------------------------------------------
__global__ __launch_bounds__(256) void rnn_kernel(
    float* childft,                    // [M,256] in: child_sum, out: ft (no restrict: aliased)
    const float* __restrict__ W,       // [256,256] row-major: W[n][k]
    const float* __restrict__ bvec,    // [256]
    const float* __restrict__ emb,     // [V,256]
    const int* __restrict__ seg_start,
    const int* __restrict__ seg_end,
    const int* __restrict__ edge_tok,
    int M)
{
    __shared__ __align__(16) float As[16][68];   // [k][m], stride 68 (16B-aligned rows)
    __shared__ float Bs[16][260];                // [k][n]
    const int t  = threadIdx.x;
    const int cy = t & 63;
    const int ry = t >> 6;
    const int m0 = blockIdx.x * 64;

    float acc[16][4];
#pragma unroll
    for (int i = 0; i < 16; ++i)
#pragma unroll
        for (int j = 0; j < 4; ++j) acc[i][j] = 0.f;

    const int ar  = t >> 2;            // 0..63 (A stage row)
    const int ak4 = (t & 3) * 4;       // A stage k offset
    const int arr = min(m0 + ar, M - 1);

    for (int kt = 0; kt < 16; ++kt) {
        const int kb = kt * 16;
        float4 av = *(const float4*)(childft + (size_t)arr * DD + kb + ak4);
        float4 bv[4];
#pragma unroll
        for (int i = 0; i < 4; ++i) {
            int fid = t + 256 * i;
            int n   = fid >> 2;
            int k4  = (fid & 3) * 4;
            bv[i] = *(const float4*)(W + (size_t)n * DD + kb + k4);
        }
        __syncthreads();               // previous tile's compute done
        As[ak4 + 0][ar] = av.x;
        As[ak4 + 1][ar] = av.y;
        As[ak4 + 2][ar] = av.z;
        As[ak4 + 3][ar] = av.w;
#pragma unroll
        for (int i = 0; i < 4; ++i) {
            int fid = t + 256 * i;
            int n   = fid >> 2;
            int k4  = (fid & 3) * 4;
            Bs[k4 + 0][n] = bv[i].x;
            Bs[k4 + 1][n] = bv[i].y;
            Bs[k4 + 2][n] = bv[i].z;
            Bs[k4 + 3][n] = bv[i].w;
        }
        __syncthreads();
#pragma unroll
        for (int kk = 0; kk < 16; ++kk) {
            float4 a0 = *(const float4*)&As[kk][ry * 16 + 0];
            float4 a1 = *(const float4*)&As[kk][ry * 16 + 4];
            float4 a2 = *(const float4*)&As[kk][ry * 16 + 8];
            float4 a3 = *(const float4*)&As[kk][ry * 16 + 12];
            float bb0 = Bs[kk][cy];
            float bb1 = Bs[kk][cy + 64];
            float bb2 = Bs[kk][cy + 128];
            float bb3 = Bs[kk][cy + 192];
            float aa[16] = {a0.x, a0.y, a0.z, a0.w, a1.x, a1.y, a1.z, a1.w,
                            a2.x, a2.y, a2.z, a2.w, a3.x, a3.y, a3.z, a3.w};
            float bb[4]  = {bb0, bb1, bb2, bb3};
#pragma unroll
            for (int i = 0; i < 16; ++i)
#pragma unroll
                for (int j = 0; j < 4; ++j)
                    acc[i][j] = fmaf(aa[i], bb[j], acc[i][j]);
        }
    }

    float bias[4];
#pragma unroll
    for (int j = 0; j < 4; ++j) bias[j] = bvec[cy + 64 * j];

#pragma unroll
    for (int i = 0; i < 16; ++i) {
        int m = m0 + ry * 16 + i;      // wave-uniform
        if (m < M) {
            int ls = seg_start[m];
            int le = seg_end[m];
            int tok = edge_tok[le - 1];
            bool multi = (le - ls) > 1;
            const float* lrow = emb + (size_t)tok * DD;
#pragma unroll
            for (int j = 0; j < 4; ++j) {
                int c = cy + 64 * j;
                float v = fmaxf(acc[i][j] + bias[j], 0.f);
                childft[(size_t)m * DD + c] = lrow[c] + (multi ? v : 0.f);
            }
        }
    }
}

// ---------------------------------------------------------------------------
// Kernel 4: classifier GEMM  out[m][c] = sum_k ft[m][k]*Wc[c][k] + bc[c]
//   tile: 64 rows x 104 cols per 256-thread block, K-tile = 32.
//   thread: ry = t/64 -> rows ry*16+i ; cy = t%64 -> cols cy, cy+64 (cy<40).
// ---------------------------------------------------------------------------
__global__ __launch_bounds__(256) void cls_kernel(
    const float* __restrict__ ft,   // [M,256]
    const float* __restrict__ Wc,   // [104,256]
    const float* __restrict__ bc,   // [104]
    float* __restrict__ out,        // [M,104]
    int M)
{
    __shared__ __align__(16) float As[32][68];
    __shared__ float Bs[32][105];
    const int t  = threadIdx.x;
    const int cy = t & 63;
    const int ry = t >> 6;
    const int m0 = blockIdx.x * 64;

    float acc[16][2];
#pragma unroll
    for (int i = 0; i < 16; ++i) { acc[i][0] = 0.f; acc[i][1] = 0.f; }

    for (int kt = 0; kt < 8; ++kt) {
        const int kb = kt * 32;
        float4 av[2];
        int arN[2], ak4N[2];
#pragma unroll
        for (int i = 0; i < 2; ++i) {
            int fid = t + 256 * i;
            arN[i]  = fid >> 3;              // 0..63
            ak4N[i] = (fid & 7) * 4;
            int rr = min(m0 + arN[i], M - 1);
            av[i] = *(const float4*)(ft + (size_t)rr * DD + kb + ak4N[i]);
        }
        float4 bv[4];
        int bnN[4], bk4N[4];
#pragma unroll
        for (int i = 0; i < 4; ++i) {
            int fid = t + 256 * i;
            bnN[i]  = fid >> 3;
            bk4N[i] = (fid & 7) * 4;
            if (fid < 832)
                bv[i] = *(const float4*)(Wc + (size_t)bnN[i] * DD + kb + bk4N[i]);
        }
        __syncthreads();
#pragma unroll
        for (int i = 0; i < 2; ++i) {
            As[ak4N[i] + 0][arN[i]] = av[i].x;
            As[ak4N[i] + 1][arN[i]] = av[i].y;
            As[ak4N[i] + 2][arN[i]] = av[i].z;
            As[ak4N[i] + 3][arN[i]] = av[i].w;
        }
#pragma unroll
        for (int i = 0; i < 4; ++i) {
            int fid = t + 256 * i;
            if (fid < 832) {
                Bs[bk4N[i] + 0][bnN[i]] = bv[i].x;
                Bs[bk4N[i] + 1][bnN[i]] = bv[i].y;
                Bs[bk4N[i] + 2][bnN[i]] = bv[i].z;
                Bs[bk4N[i] + 3][bnN[i]] = bv[i].w;
            }
        }
        __syncthreads();
#pragma unroll
        for (int kk = 0; kk < 32; ++kk) {
            float4 a0 = *(const float4*)&As[kk][ry * 16 + 0];
            float4 a1 = *(const float4*)&As[kk][ry * 16 + 4];
            float4 a2 = *(const float4*)&As[kk][ry * 16 + 8];
            float4 a3 = *(const float4*)&As[kk][ry * 16 + 12];
            float b0 = Bs[kk][cy];
            float b1 = (cy < 40) ? Bs[kk][cy + 64] : 0.f;
            float aa[16] = {a0.x, a0.y, a0.z, a0.w, a1.x, a1.y, a1.z, a1.w,
                            a2.x, a2.y, a2.z, a2.w, a3.x, a3.y, a3.z, a3.w};
#pragma unroll
            for (int i = 0; i < 16; ++i) {
                acc[i][0] = fmaf(aa[i], b0, acc[i][0]);
                acc[i][1] = fmaf(aa[i], b1, acc[i][1]);
            }
        }
        __syncthreads();
    }

    float bc0 = bc[cy];
    float bc1 = (cy < 40) ? bc[cy + 64] : 0.f;
#pragma unroll
    for (int i = 0; i < 16; ++i) {
        int m = m0 + ry * 16 + i;
        if (m < M) {
            out[(size_t)m * CC + cy] = acc[i][0] + bc0;
            if (cy < 40)
                out[(size_t)m * CC + cy + 64] = acc[i][1] + bc1;
        }
    }
}

// ---------------------------------------------------------------------------
extern "C" void kernel_launch(void* const* d_in, const int* in_sizes, int n_in,
                              void* d_out, int out_size, void* d_ws, size_t ws_size,
                              hipStream_t stream)
{
    const float* emb      = (const float*)d_in[0];
    const float* W        = (const float*)d_in[1];
    const float* bvec     = (const float*)d_in[2];
    const float* Wc       = (const float*)d_in[3];
    const float* bc       = (const float*)d_in[4];
    const int*   token_id = (const int*)d_in[5];
    const int*   src_idx  = (const int*)d_in[6];
    const int*   dst_idx  = (const int*)d_in[7];
    float*       out      = (float*)d_out;

    const int E     = in_sizes[6];
    const int n_dst = out_size / CC;

    char* ws = (char*)d_ws;
    size_t off = 0;
    auto alloc = [&](size_t bytes) {
        void* p = ws + off;
        off = (off + bytes + 255) & ~(size_t)255;
        return p;
    };
    int*   seg_start = (int*)alloc((size_t)n_dst * sizeof(int));
    int*   seg_end   = (int*)alloc((size_t)n_dst * sizeof(int));
    int*   edge_tok  = (int*)alloc((size_t)E * sizeof(int));
    float* child     = (float*)alloc((size_t)n_dst * DD * sizeof(float)); // also ft (in-place)
    (void)ws_size; (void)n_in;

    prep_kernel<<<(E + 255) / 256, 256, 0, stream>>>(
        token_id, src_idx, dst_idx, seg_start, seg_end, edge_tok, E);
    seg_sum_kernel<<<(n_dst + 3) / 4, 256, 0, stream>>>(
        emb, edge_tok, seg_start, seg_end, child, n_dst);
    rnn_kernel<<<(n_dst + 63) / 64, 256, 0, stream>>>(
        child, W, bvec, emb, seg_start, seg_end, edge_tok, n_dst);
    cls_kernel<<<(n_dst + 63) / 64, 256, 0, stream>>>(
        child, Wc, bc, out, n_dst);
}

// Round 2
// 375.930 us; speedup vs baseline: 2.1697x; 2.1697x over previous
//
#include <hip/hip_runtime.h>

#define DD 256
#define CC 104

// ---------------------------------------------------------------------------
// Kernel 1: per-edge prep — edge token gather + segment boundaries
// ---------------------------------------------------------------------------
__global__ void prep_kernel(const int* __restrict__ token_id,
                            const int* __restrict__ src_idx,
                            const int* __restrict__ dst_idx,
                            int* __restrict__ seg_start,
                            int* __restrict__ seg_end,
                            int* __restrict__ edge_tok,
                            int E)
{
    int e = blockIdx.x * blockDim.x + threadIdx.x;
    if (e >= E) return;
    int d = dst_idx[e];
    edge_tok[e] = token_id[src_idx[e]];
    if (e == 0 || dst_idx[e - 1] != d) seg_start[d] = e;
    if (e == E - 1 || dst_idx[e + 1] != d) seg_end[d] = e + 1;
}

// ---------------------------------------------------------------------------
// Kernel 2: one wave per dst node; lane covers 4 consecutive floats (float4).
// child_sum[d] = sum of emb[edge_tok[i]] for i in [seg_start, seg_end-1)
// ---------------------------------------------------------------------------
__global__ void seg_sum_kernel(const float* __restrict__ emb,
                               const int* __restrict__ edge_tok,
                               const int* __restrict__ seg_start,
                               const int* __restrict__ seg_end,
                               float* __restrict__ child,
                               int n_dst)
{
    int w = (blockIdx.x * blockDim.x + threadIdx.x) >> 6;
    int lane = threadIdx.x & 63;
    if (w >= n_dst) return;
    int s = seg_start[w];
    int e = seg_end[w];
    float4 acc = make_float4(0.f, 0.f, 0.f, 0.f);
    for (int i = s; i < e - 1; ++i) {
        int tok = edge_tok[i];                      // wave-uniform broadcast load
        const float4* row = (const float4*)(emb + (size_t)tok * DD);
        float4 v = row[lane];
        acc.x += v.x; acc.y += v.y; acc.z += v.z; acc.w += v.w;
    }
    ((float4*)(child + (size_t)w * DD))[lane] = acc;
}

// ---------------------------------------------------------------------------
// Kernel 3: GEMM1 + RNN epilogue, in-place: ft overwrites child_sum.
//   tile: 32 rows x 256 cols (full N), BK=16, 256 threads.
//   thread: ry = t>>6 -> rows ry*8+i (i<8, wave-uniform), cy = t&63 -> cols cy+64j.
//   acc[8][4] = 32 VGPRs; no temp arrays; unroll capped at 4 to avoid spills.
// ---------------------------------------------------------------------------
__global__ __launch_bounds__(256) void rnn_kernel(
    float* childft,                    // [M,256] in: child_sum, out: ft (aliased)
    const float* __restrict__ W,       // [256,256] row-major: W[n][k]
    const float* __restrict__ bvec,    // [256]
    const float* __restrict__ emb,     // [V,256]
    const int* __restrict__ seg_start,
    const int* __restrict__ seg_end,
    const int* __restrict__ edge_tok,
    int M)
{
    __shared__ __align__(16) float As[16][36];   // [k][m], stride 36 (16B-aligned)
    __shared__ float Bs[16][260];                // [k][n]
    const int t  = threadIdx.x;
    const int cy = t & 63;
    const int ry = t >> 6;
    const int m0 = blockIdx.x * 32;

    float acc[8][4];
#pragma unroll
    for (int i = 0; i < 8; ++i)
#pragma unroll
        for (int j = 0; j < 4; ++j) acc[i][j] = 0.f;

    // A-stage map: 32 m x 16 k = 128 float4, threads t<128
    const int ar  = t >> 2;            // 0..63 (only <32 used)
    const int ak4 = (t & 3) * 4;
    const int arr = min(m0 + min(ar, 31), M - 1);

    for (int kt = 0; kt < 16; ++kt) {
        const int kb = kt * 16;
        float4 av = make_float4(0.f, 0.f, 0.f, 0.f);
        if (t < 128)
            av = *(const float4*)(childft + (size_t)arr * DD + kb + ak4);
        float4 bv[4];
#pragma unroll
        for (int i = 0; i < 4; ++i) {
            int fid = t + 256 * i;
            int n   = fid >> 2;          // 0..255
            int k4  = (fid & 3) * 4;
            bv[i] = *(const float4*)(W + (size_t)n * DD + kb + k4);
        }
        __syncthreads();               // previous tile's compute done
        if (t < 128) {
            As[ak4 + 0][ar] = av.x;
            As[ak4 + 1][ar] = av.y;
            As[ak4 + 2][ar] = av.z;
            As[ak4 + 3][ar] = av.w;
        }
#pragma unroll
        for (int i = 0; i < 4; ++i) {
            int fid = t + 256 * i;
            int n   = fid >> 2;
            int k4  = (fid & 3) * 4;
            Bs[k4 + 0][n] = bv[i].x;
            Bs[k4 + 1][n] = bv[i].y;
            Bs[k4 + 2][n] = bv[i].z;
            Bs[k4 + 3][n] = bv[i].w;
        }
        __syncthreads();
#pragma unroll 4
        for (int kk = 0; kk < 16; ++kk) {
            float4 a0 = *(const float4*)&As[kk][ry * 8 + 0];  // broadcast
            float4 a1 = *(const float4*)&As[kk][ry * 8 + 4];
            float b0 = Bs[kk][cy];
            float b1 = Bs[kk][cy + 64];
            float b2 = Bs[kk][cy + 128];
            float b3 = Bs[kk][cy + 192];
            acc[0][0] = fmaf(a0.x, b0, acc[0][0]); acc[0][1] = fmaf(a0.x, b1, acc[0][1]);
            acc[0][2] = fmaf(a0.x, b2, acc[0][2]); acc[0][3] = fmaf(a0.x, b3, acc[0][3]);
            acc[1][0] = fmaf(a0.y, b0, acc[1][0]); acc[1][1] = fmaf(a0.y, b1, acc[1][1]);
            acc[1][2] = fmaf(a0.y, b2, acc[1][2]); acc[1][3] = fmaf(a0.y, b3, acc[1][3]);
            acc[2][0] = fmaf(a0.z, b0, acc[2][0]); acc[2][1] = fmaf(a0.z, b1, acc[2][1]);
            acc[2][2] = fmaf(a0.z, b2, acc[2][2]); acc[2][3] = fmaf(a0.z, b3, acc[2][3]);
            acc[3][0] = fmaf(a0.w, b0, acc[3][0]); acc[3][1] = fmaf(a0.w, b1, acc[3][1]);
            acc[3][2] = fmaf(a0.w, b2, acc[3][2]); acc[3][3] = fmaf(a0.w, b3, acc[3][3]);
            acc[4][0] = fmaf(a1.x, b0, acc[4][0]); acc[4][1] = fmaf(a1.x, b1, acc[4][1]);
            acc[4][2] = fmaf(a1.x, b2, acc[4][2]); acc[4][3] = fmaf(a1.x, b3, acc[4][3]);
            acc[5][0] = fmaf(a1.y, b0, acc[5][0]); acc[5][1] = fmaf(a1.y, b1, acc[5][1]);
            acc[5][2] = fmaf(a1.y, b2, acc[5][2]); acc[5][3] = fmaf(a1.y, b3, acc[5][3]);
            acc[6][0] = fmaf(a1.z, b0, acc[6][0]); acc[6][1] = fmaf(a1.z, b1, acc[6][1]);
            acc[6][2] = fmaf(a1.z, b2, acc[6][2]); acc[6][3] = fmaf(a1.z, b3, acc[6][3]);
            acc[7][0] = fmaf(a1.w, b0, acc[7][0]); acc[7][1] = fmaf(a1.w, b1, acc[7][1]);
            acc[7][2] = fmaf(a1.w, b2, acc[7][2]); acc[7][3] = fmaf(a1.w, b3, acc[7][3]);
        }
    }

    float bias[4];
#pragma unroll
    for (int j = 0; j < 4; ++j) bias[j] = bvec[cy + 64 * j];

#pragma unroll
    for (int i = 0; i < 8; ++i) {
        int m = m0 + ry * 8 + i;       // wave-uniform
        if (m < M) {
            int ls = seg_start[m];
            int le = seg_end[m];
            int tok = edge_tok[le - 1];
            bool multi = (le - ls) > 1;
            const float* lrow = emb + (size_t)tok * DD;
#pragma unroll
            for (int j = 0; j < 4; ++j) {
                int c = cy + 64 * j;
                float v = fmaxf(acc[i][j] + bias[j], 0.f);
                childft[(size_t)m * DD + c] = lrow[c] + (multi ? v : 0.f);
            }
        }
    }
}

// ---------------------------------------------------------------------------
// Kernel 4: classifier GEMM  out[m][c] = sum_k ft[m][k]*Wc[c][k] + bc[c]
//   tile: 32 rows x 104 cols (padded to 128 in LDS), BK=32, 256 threads.
//   thread: ry = t>>6 -> rows ry*8+i ; cy = t&63 -> cols cy, cy+64.
//   Bs zero-padded for n in [104,128) -> branch-free inner loop.
//   acc[8][2] = 16 VGPRs; unroll capped at 4. (R1: VGPR=256 + 780MB spills)
// ---------------------------------------------------------------------------
__global__ __launch_bounds__(256) void cls_kernel(
    const float* __restrict__ ft,   // [M,256]
    const float* __restrict__ Wc,   // [104,256]
    const float* __restrict__ bc,   // [104]
    float* __restrict__ out,        // [M,104]
    int M)
{
    __shared__ __align__(16) float As[32][36];   // [k][m]
    __shared__ float Bs[32][132];                // [k][n], n padded to 128
    const int t  = threadIdx.x;
    const int cy = t & 63;
    const int ry = t >> 6;
    const int m0 = blockIdx.x * 32;

    float acc[8][2];
#pragma unroll
    for (int i = 0; i < 8; ++i) { acc[i][0] = 0.f; acc[i][1] = 0.f; }

    // A-stage: 32 m x 32 k = 256 float4, one per thread
    const int ar  = t >> 3;            // 0..31
    const int ak4 = (t & 7) * 4;
    const int arr = min(m0 + ar, M - 1);

    for (int kt = 0; kt < 8; ++kt) {
        const int kb = kt * 32;
        float4 av = *(const float4*)(ft + (size_t)arr * DD + kb + ak4);
        // B-stage: 128 n x 32 k = 1024 float4 slots; n>=104 zero-filled
        float4 bv[4];
#pragma unroll
        for (int i = 0; i < 4; ++i) {
            int fid = t + 256 * i;
            int bn  = fid >> 3;          // 0..127
            int bk4 = (fid & 7) * 4;
            bv[i] = (bn < CC) ? *(const float4*)(Wc + (size_t)bn * DD + kb + bk4)
                              : make_float4(0.f, 0.f, 0.f, 0.f);
        }
        __syncthreads();
        As[ak4 + 0][ar] = av.x;
        As[ak4 + 1][ar] = av.y;
        As[ak4 + 2][ar] = av.z;
        As[ak4 + 3][ar] = av.w;
#pragma unroll
        for (int i = 0; i < 4; ++i) {
            int fid = t + 256 * i;
            int bn  = fid >> 3;
            int bk4 = (fid & 7) * 4;
            Bs[bk4 + 0][bn] = bv[i].x;
            Bs[bk4 + 1][bn] = bv[i].y;
            Bs[bk4 + 2][bn] = bv[i].z;
            Bs[bk4 + 3][bn] = bv[i].w;
        }
        __syncthreads();
#pragma unroll 4
        for (int kk = 0; kk < 32; ++kk) {
            float4 a0 = *(const float4*)&As[kk][ry * 8 + 0];  // broadcast
            float4 a1 = *(const float4*)&As[kk][ry * 8 + 4];
            float b0 = Bs[kk][cy];
            float b1 = Bs[kk][cy + 64];
            acc[0][0] = fmaf(a0.x, b0, acc[0][0]); acc[0][1] = fmaf(a0.x, b1, acc[0][1]);
            acc[1][0] = fmaf(a0.y, b0, acc[1][0]); acc[1][1] = fmaf(a0.y, b1, acc[1][1]);
            acc[2][0] = fmaf(a0.z, b0, acc[2][0]); acc[2][1] = fmaf(a0.z, b1, acc[2][1]);
            acc[3][0] = fmaf(a0.w, b0, acc[3][0]); acc[3][1] = fmaf(a0.w, b1, acc[3][1]);
            acc[4][0] = fmaf(a1.x, b0, acc[4][0]); acc[4][1] = fmaf(a1.x, b1, acc[4][1]);
            acc[5][0] = fmaf(a1.y, b0, acc[5][0]); acc[5][1] = fmaf(a1.y, b1, acc[5][1]);
            acc[6][0] = fmaf(a1.z, b0, acc[6][0]); acc[6][1] = fmaf(a1.z, b1, acc[6][1]);
            acc[7][0] = fmaf(a1.w, b0, acc[7][0]); acc[7][1] = fmaf(a1.w, b1, acc[7][1]);
        }
    }

    float bc0 = bc[cy];
    float bc1 = (cy < CC - 64) ? bc[cy + 64] : 0.f;
#pragma unroll
    for (int i = 0; i < 8; ++i) {
        int m = m0 + ry * 8 + i;
        if (m < M) {
            out[(size_t)m * CC + cy] = acc[i][0] + bc0;
            if (cy < CC - 64)
                out[(size_t)m * CC + cy + 64] = acc[i][1] + bc1;
        }
    }
}

// ---------------------------------------------------------------------------
extern "C" void kernel_launch(void* const* d_in, const int* in_sizes, int n_in,
                              void* d_out, int out_size, void* d_ws, size_t ws_size,
                              hipStream_t stream)
{
    const float* emb      = (const float*)d_in[0];
    const float* W        = (const float*)d_in[1];
    const float* bvec     = (const float*)d_in[2];
    const float* Wc       = (const float*)d_in[3];
    const float* bc       = (const float*)d_in[4];
    const int*   token_id = (const int*)d_in[5];
    const int*   src_idx  = (const int*)d_in[6];
    const int*   dst_idx  = (const int*)d_in[7];
    float*       out      = (float*)d_out;

    const int E     = in_sizes[6];
    const int n_dst = out_size / CC;

    char* ws = (char*)d_ws;
    size_t off = 0;
    auto alloc = [&](size_t bytes) {
        void* p = ws + off;
        off = (off + bytes + 255) & ~(size_t)255;
        return p;
    };
    int*   seg_start = (int*)alloc((size_t)n_dst * sizeof(int));
    int*   seg_end   = (int*)alloc((size_t)n_dst * sizeof(int));
    int*   edge_tok  = (int*)alloc((size_t)E * sizeof(int));
    float* child     = (float*)alloc((size_t)n_dst * DD * sizeof(float)); // also ft
    (void)ws_size; (void)n_in;

    prep_kernel<<<(E + 255) / 256, 256, 0, stream>>>(
        token_id, src_idx, dst_idx, seg_start, seg_end, edge_tok, E);
    seg_sum_kernel<<<(n_dst + 3) / 4, 256, 0, stream>>>(
        emb, edge_tok, seg_start, seg_end, child, n_dst);
    rnn_kernel<<<(n_dst + 31) / 32, 256, 0, stream>>>(
        child, W, bvec, emb, seg_start, seg_end, edge_tok, n_dst);
    cls_kernel<<<(n_dst + 31) / 32, 256, 0, stream>>>(
        child, Wc, bc, out, n_dst);
}

// Round 3
// 291.452 us; speedup vs baseline: 2.7986x; 1.2899x over previous
//
#include <hip/hip_runtime.h>
#include <hip/hip_bf16.h>

#define DD 256
#define CC 104

typedef __bf16 bf16x8 __attribute__((ext_vector_type(8)));
typedef float  f32x4  __attribute__((ext_vector_type(4)));

__device__ inline float bu2f(unsigned short u) {
    return __uint_as_float(((unsigned)u) << 16);
}
__device__ inline unsigned short f2bu(float f) {
    __hip_bfloat16 h = __float2bfloat16(f);
    return *reinterpret_cast<unsigned short*>(&h);
}

// ---------------------------------------------------------------------------
// Kernel 1: per-edge prep — edge token gather + segment boundaries
// ---------------------------------------------------------------------------
__global__ void prep_kernel(const int* __restrict__ token_id,
                            const int* __restrict__ src_idx,
                            const int* __restrict__ dst_idx,
                            int* __restrict__ seg_start,
                            int* __restrict__ seg_end,
                            int* __restrict__ edge_tok,
                            int E)
{
    int e = blockIdx.x * blockDim.x + threadIdx.x;
    if (e >= E) return;
    int d = dst_idx[e];
    edge_tok[e] = token_id[src_idx[e]];
    if (e == 0 || dst_idx[e - 1] != d) seg_start[d] = e;
    if (e == E - 1 || dst_idx[e + 1] != d) seg_end[d] = e + 1;
}

// ---------------------------------------------------------------------------
// Kernel 2: fp32 -> bf16 conversion of emb, W, and Wc (Wc zero-padded to 128
// rows so the cls MFMA needs no N guard). One float4 -> 4 bf16 per thread.
// ---------------------------------------------------------------------------
__global__ void convert_kernel(const float* __restrict__ emb,
                               const float* __restrict__ W,
                               const float* __restrict__ Wc,
                               __hip_bfloat16* __restrict__ embb,
                               __hip_bfloat16* __restrict__ Wb,
                               __hip_bfloat16* __restrict__ Wcb,
                               int nE4)   // V*256/4
{
    const int nW4  = DD * DD / 4;      // 16384
    const int nWc4 = 128 * DD / 4;     // 8192 (incl pad)
    int i = blockIdx.x * blockDim.x + threadIdx.x;
    float4 v;
    __hip_bfloat16* dst;
    if (i < nE4) {
        v = ((const float4*)emb)[i];
        dst = embb + (size_t)i * 4;
    } else if (i < nE4 + nW4) {
        int j = i - nE4;
        v = ((const float4*)W)[j];
        dst = Wb + (size_t)j * 4;
    } else if (i < nE4 + nW4 + nWc4) {
        int j = i - nE4 - nW4;
        v = (j < CC * DD / 4) ? ((const float4*)Wc)[j]
                              : make_float4(0.f, 0.f, 0.f, 0.f);
        dst = Wcb + (size_t)j * 4;
    } else return;
    ushort4 o;
    o.x = f2bu(v.x); o.y = f2bu(v.y); o.z = f2bu(v.z); o.w = f2bu(v.w);
    *(ushort4*)dst = o;
}

// ---------------------------------------------------------------------------
// Kernel 3: one wave per dst node; lane covers 4 bf16 (8B). fp32 accumulate.
// child_bf16[d] = sum of embb[edge_tok[i]] for i in [seg_start, seg_end-1)
// ---------------------------------------------------------------------------
__global__ void seg_sum_kernel(const __hip_bfloat16* __restrict__ embb,
                               const int* __restrict__ edge_tok,
                               const int* __restrict__ seg_start,
                               const int* __restrict__ seg_end,
                               __hip_bfloat16* __restrict__ childb,
                               int n_dst)
{
    int w = (blockIdx.x * blockDim.x + threadIdx.x) >> 6;
    int lane = threadIdx.x & 63;
    if (w >= n_dst) return;
    int s = seg_start[w];
    int e = seg_end[w] - 1;            // exclude last edge (RNN current input)
    float4 acc = make_float4(0.f, 0.f, 0.f, 0.f);
    int i = s;
    for (; i + 1 < e; i += 2) {        // 2-edge unroll: two loads in flight
        int t0 = edge_tok[i];
        int t1 = edge_tok[i + 1];
        ushort4 v0 = ((const ushort4*)(embb + (size_t)t0 * DD))[lane];
        ushort4 v1 = ((const ushort4*)(embb + (size_t)t1 * DD))[lane];
        acc.x += bu2f(v0.x) + bu2f(v1.x);
        acc.y += bu2f(v0.y) + bu2f(v1.y);
        acc.z += bu2f(v0.z) + bu2f(v1.z);
        acc.w += bu2f(v0.w) + bu2f(v1.w);
    }
    if (i < e) {
        int t0 = edge_tok[i];
        ushort4 v0 = ((const ushort4*)(embb + (size_t)t0 * DD))[lane];
        acc.x += bu2f(v0.x);
        acc.y += bu2f(v0.y);
        acc.z += bu2f(v0.z);
        acc.w += bu2f(v0.w);
    }
    ushort4 o;
    o.x = f2bu(acc.x); o.y = f2bu(acc.y); o.z = f2bu(acc.z); o.w = f2bu(acc.w);
    ((ushort4*)(childb + (size_t)w * DD))[lane] = o;
}

// ---------------------------------------------------------------------------
// Kernel 4: RNN GEMM via MFMA 16x16x32 bf16, in-place (ft overwrites child).
//   One wave owns a 16-row x 256-col strip: 16 n-tiles, acc = 16 x f32x4.
//   A-frag: child[m0+(lane&15)][k0 + quad*8 + j]  (contiguous 16B load)
//   B-frag: W[nt*16+(lane&15)][k0 + quad*8 + j]   (contiguous 16B load, L2-hot)
//   No LDS, no barriers. Epilogue: ft = last_msg + (deg>1 ? relu(acc+b) : 0).
//   D-layout: col = lane&15, row = quad*4 + reg.
// ---------------------------------------------------------------------------
__global__ __launch_bounds__(256) void rnn_mfma(
    __hip_bfloat16* childft,            // [M,256] in: child_sum, out: ft
    const __hip_bfloat16* __restrict__ Wb,    // [256,256] bf16, W[n][k]
    const float* __restrict__ bvec,     // [256]
    const __hip_bfloat16* __restrict__ embb,  // [V,256] bf16
    const int* __restrict__ seg_start,
    const int* __restrict__ seg_end,
    const int* __restrict__ edge_tok,
    int M)
{
    int wave = blockIdx.x * 4 + (threadIdx.x >> 6);
    int lane = threadIdx.x & 63;
    int m0 = wave * 16;
    if (m0 >= M) return;
    int quad = lane >> 4;
    int l16  = lane & 15;

    f32x4 acc[16];
#pragma unroll
    for (int nt = 0; nt < 16; ++nt) acc[nt] = (f32x4){0.f, 0.f, 0.f, 0.f};

    int ar = min(m0 + l16, M - 1);
    const __hip_bfloat16* arow = childft + (size_t)ar * DD + quad * 8;
    const __hip_bfloat16* brow = Wb + (size_t)l16 * DD + quad * 8;

    for (int k0 = 0; k0 < DD; k0 += 32) {
        bf16x8 a = *(const bf16x8*)(arow + k0);
#pragma unroll
        for (int nt = 0; nt < 16; ++nt) {
            bf16x8 b = *(const bf16x8*)(brow + (size_t)nt * 16 * DD + k0);
            acc[nt] = __builtin_amdgcn_mfma_f32_16x16x32_bf16(a, b, acc[nt], 0, 0, 0);
        }
    }

    float bias[16];
#pragma unroll
    for (int nt = 0; nt < 16; ++nt) bias[nt] = bvec[nt * 16 + l16];

#pragma unroll
    for (int r = 0; r < 4; ++r) {
        int m = m0 + quad * 4 + r;
        if (m < M) {
            int le  = seg_end[m];
            bool multi = (le - seg_start[m]) > 1;
            int tok = edge_tok[le - 1];
            const __hip_bfloat16* lrow = embb + (size_t)tok * DD;
#pragma unroll
            for (int nt = 0; nt < 16; ++nt) {
                int c = nt * 16 + l16;
                float last = __bfloat162float(lrow[c]);
                float v = multi ? fmaxf(acc[nt][r] + bias[nt], 0.f) : 0.f;
                childft[(size_t)m * DD + c] = __float2bfloat16(last + v);
            }
        }
    }
}

// ---------------------------------------------------------------------------
// Kernel 5: classifier GEMM via MFMA. Wcb is zero-padded to 128 rows ->
// 8 n-tiles, no guards in the K-loop. Output fp32, only c<104 stored.
// ---------------------------------------------------------------------------
__global__ __launch_bounds__(256) void cls_mfma(
    const __hip_bfloat16* __restrict__ ftb,   // [M,256] bf16
    const __hip_bfloat16* __restrict__ Wcb,   // [128,256] bf16 (padded)
    const float* __restrict__ bc,             // [104]
    float* __restrict__ out,                  // [M,104]
    int M)
{
    int wave = blockIdx.x * 4 + (threadIdx.x >> 6);
    int lane = threadIdx.x & 63;
    int m0 = wave * 16;
    if (m0 >= M) return;
    int quad = lane >> 4;
    int l16  = lane & 15;

    f32x4 acc[8];
#pragma unroll
    for (int nt = 0; nt < 8; ++nt) acc[nt] = (f32x4){0.f, 0.f, 0.f, 0.f};

    int ar = min(m0 + l16, M - 1);
    const __hip_bfloat16* arow = ftb + (size_t)ar * DD + quad * 8;
    const __hip_bfloat16* brow = Wcb + (size_t)l16 * DD + quad * 8;

    for (int k0 = 0; k0 < DD; k0 += 32) {
        bf16x8 a = *(const bf16x8*)(arow + k0);
#pragma unroll
        for (int nt = 0; nt < 8; ++nt) {
            bf16x8 b = *(const bf16x8*)(brow + (size_t)nt * 16 * DD + k0);
            acc[nt] = __builtin_amdgcn_mfma_f32_16x16x32_bf16(a, b, acc[nt], 0, 0, 0);
        }
    }

    float bias[8];
#pragma unroll
    for (int nt = 0; nt < 8; ++nt) {
        int c = nt * 16 + l16;
        bias[nt] = (c < CC) ? bc[c] : 0.f;
    }

#pragma unroll
    for (int r = 0; r < 4; ++r) {
        int m = m0 + quad * 4 + r;
        if (m < M) {
#pragma unroll
            for (int nt = 0; nt < 8; ++nt) {
                int c = nt * 16 + l16;
                if (c < CC)
                    out[(size_t)m * CC + c] = acc[nt][r] + bias[nt];
            }
        }
    }
}

// ---------------------------------------------------------------------------
extern "C" void kernel_launch(void* const* d_in, const int* in_sizes, int n_in,
                              void* d_out, int out_size, void* d_ws, size_t ws_size,
                              hipStream_t stream)
{
    const float* emb      = (const float*)d_in[0];
    const float* W        = (const float*)d_in[1];
    const float* bvec     = (const float*)d_in[2];
    const float* Wc       = (const float*)d_in[3];
    const float* bc       = (const float*)d_in[4];
    const int*   token_id = (const int*)d_in[5];
    const int*   src_idx  = (const int*)d_in[6];
    const int*   dst_idx  = (const int*)d_in[7];
    float*       out      = (float*)d_out;

    const int E     = in_sizes[6];
    const int V     = in_sizes[5];       // token_id has N_SRC entries; emb rows = in_sizes[0]/DD
    const int Vemb  = in_sizes[0] / DD;
    const int n_dst = out_size / CC;
    (void)V; (void)n_in; (void)ws_size;

    char* ws = (char*)d_ws;
    size_t off = 0;
    auto alloc = [&](size_t bytes) {
        void* p = ws + off;
        off = (off + bytes + 255) & ~(size_t)255;
        return p;
    };
    int* seg_start = (int*)alloc((size_t)n_dst * sizeof(int));
    int* seg_end   = (int*)alloc((size_t)n_dst * sizeof(int));
    int* edge_tok  = (int*)alloc((size_t)E * sizeof(int));
    __hip_bfloat16* childb = (__hip_bfloat16*)alloc((size_t)n_dst * DD * 2); // also ft
    __hip_bfloat16* embb   = (__hip_bfloat16*)alloc((size_t)Vemb * DD * 2);
    __hip_bfloat16* Wb     = (__hip_bfloat16*)alloc((size_t)DD * DD * 2);
    __hip_bfloat16* Wcb    = (__hip_bfloat16*)alloc((size_t)128 * DD * 2);

    const int nE4 = Vemb * (DD / 4);
    const int cvt_total = nE4 + DD * DD / 4 + 128 * DD / 4;

    prep_kernel<<<(E + 255) / 256, 256, 0, stream>>>(
        token_id, src_idx, dst_idx, seg_start, seg_end, edge_tok, E);
    convert_kernel<<<(cvt_total + 255) / 256, 256, 0, stream>>>(
        emb, W, Wc, embb, Wb, Wcb, nE4);
    seg_sum_kernel<<<(n_dst + 3) / 4, 256, 0, stream>>>(
        embb, edge_tok, seg_start, seg_end, childb, n_dst);
    const int waves = (n_dst + 15) / 16;
    rnn_mfma<<<(waves + 3) / 4, 256, 0, stream>>>(
        childb, Wb, bvec, embb, seg_start, seg_end, edge_tok, n_dst);
    cls_mfma<<<(waves + 3) / 4, 256, 0, stream>>>(
        childb, Wcb, bc, out, n_dst);
}

// Round 4
// 221.986 us; speedup vs baseline: 3.6743x; 1.3129x over previous
//
#include <hip/hip_runtime.h>
#include <hip/hip_bf16.h>

#define DD 256
#define CC 104

typedef __bf16 bf16x8 __attribute__((ext_vector_type(8)));
typedef float  f32x4  __attribute__((ext_vector_type(4)));

__device__ inline unsigned short f2bu(float f) {
    __hip_bfloat16 h = __float2bfloat16(f);
    return *reinterpret_cast<unsigned short*>(&h);
}

// ---------------------------------------------------------------------------
// Kernel 1: per-edge prep — edge token gather + segment boundaries
// ---------------------------------------------------------------------------
__global__ void prep_kernel(const int* __restrict__ token_id,
                            const int* __restrict__ src_idx,
                            const int* __restrict__ dst_idx,
                            int* __restrict__ seg_start,
                            int* __restrict__ seg_end,
                            int* __restrict__ edge_tok,
                            int E)
{
    int e = blockIdx.x * blockDim.x + threadIdx.x;
    if (e >= E) return;
    int d = dst_idx[e];
    edge_tok[e] = token_id[src_idx[e]];
    if (e == 0 || dst_idx[e - 1] != d) seg_start[d] = e;
    if (e == E - 1 || dst_idx[e + 1] != d) seg_end[d] = e + 1;
}

// ---------------------------------------------------------------------------
// Kernel 2: fp32 -> bf16 conversion of emb, W, and Wc (Wc zero-padded to 128
// rows so the cls MFMA needs no N guard).
// ---------------------------------------------------------------------------
__global__ void convert_kernel(const float* __restrict__ emb,
                               const float* __restrict__ W,
                               const float* __restrict__ Wc,
                               __hip_bfloat16* __restrict__ embb,
                               __hip_bfloat16* __restrict__ Wb,
                               __hip_bfloat16* __restrict__ Wcb,
                               int nE4)
{
    const int nW4  = DD * DD / 4;
    const int nWc4 = 128 * DD / 4;
    int i = blockIdx.x * blockDim.x + threadIdx.x;
    float4 v;
    __hip_bfloat16* dst;
    if (i < nE4) {
        v = ((const float4*)emb)[i];
        dst = embb + (size_t)i * 4;
    } else if (i < nE4 + nW4) {
        int j = i - nE4;
        v = ((const float4*)W)[j];
        dst = Wb + (size_t)j * 4;
    } else if (i < nE4 + nW4 + nWc4) {
        int j = i - nE4 - nW4;
        v = (j < CC * DD / 4) ? ((const float4*)Wc)[j]
                              : make_float4(0.f, 0.f, 0.f, 0.f);
        dst = Wcb + (size_t)j * 4;
    } else return;
    ushort4 o;
    o.x = f2bu(v.x); o.y = f2bu(v.y); o.z = f2bu(v.z); o.w = f2bu(v.w);
    *(ushort4*)dst = o;
}

// ---------------------------------------------------------------------------
// Kernel 3: segment sum. One wave per dst; half-wave h covers edge i+h,
// 32 lanes x 16B span the 512B row. Unroll 2 -> 4 loads in flight.
// ---------------------------------------------------------------------------
__global__ void seg_sum_kernel(const __hip_bfloat16* __restrict__ embb,
                               const int* __restrict__ edge_tok,
                               const int* __restrict__ seg_start,
                               const int* __restrict__ seg_end,
                               __hip_bfloat16* __restrict__ childb,
                               int n_dst)
{
    int w = (blockIdx.x * blockDim.x + threadIdx.x) >> 6;
    int lane = threadIdx.x & 63;
    if (w >= n_dst) return;
    int h   = lane >> 5;
    int l32 = lane & 31;
    int s = seg_start[w];
    int e = seg_end[w] - 1;          // exclude last edge (RNN current input)
    float acc[8] = {0.f,0.f,0.f,0.f,0.f,0.f,0.f,0.f};

    auto accum = [&](int tok) {
        uint4 u = *(const uint4*)(embb + (size_t)tok * DD + l32 * 8);
        const unsigned* ud = (const unsigned*)&u;
#pragma unroll
        for (int d = 0; d < 4; ++d) {
            acc[2*d]   += __uint_as_float(ud[d] << 16);
            acc[2*d+1] += __uint_as_float(ud[d] & 0xffff0000u);
        }
    };

    int i = s + h;
    for (; i + 2 < e; i += 4) {
        int t0 = edge_tok[i];
        int t1 = edge_tok[i + 2];
        uint4 u0 = *(const uint4*)(embb + (size_t)t0 * DD + l32 * 8);
        uint4 u1 = *(const uint4*)(embb + (size_t)t1 * DD + l32 * 8);
        const unsigned* a0 = (const unsigned*)&u0;
        const unsigned* a1 = (const unsigned*)&u1;
#pragma unroll
        for (int d = 0; d < 4; ++d) {
            acc[2*d]   += __uint_as_float(a0[d] << 16) + __uint_as_float(a1[d] << 16);
            acc[2*d+1] += __uint_as_float(a0[d] & 0xffff0000u) + __uint_as_float(a1[d] & 0xffff0000u);
        }
    }
    if (i < e) accum(edge_tok[i]);

#pragma unroll
    for (int j = 0; j < 8; ++j) acc[j] += __shfl_xor(acc[j], 32, 64);

    if (h == 0) {
        uint4 o;
        unsigned* od = (unsigned*)&o;
#pragma unroll
        for (int d = 0; d < 4; ++d)
            od[d] = (unsigned)f2bu(acc[2*d]) | ((unsigned)f2bu(acc[2*d+1]) << 16);
        *(uint4*)(childb + (size_t)w * DD + l32 * 8) = o;
    }
}

// ---------------------------------------------------------------------------
// Kernel 4: RNN GEMM via MFMA, W staged in LDS in FRAGMENT ORDER.
//   Block = 4 waves, 128 rows; wave = 32 rows (2 m-tiles) x 256 cols.
//   Two 64KB staging phases (K 0..127, 128..255); frag group g=(k0l*16+nt)
//   is 1KB, lane-contiguous -> ds_read_b128, no conflicts.
//   A-frags hoisted per phase (8 x 16B global loads) before the barrier.
//   In-place ft: blocks touch only their own 128 rows -> race-free.
// ---------------------------------------------------------------------------
__global__ __launch_bounds__(256, 2) void rnn_mfma(
    __hip_bfloat16* childft,                   // [M,256] in: child, out: ft
    const __hip_bfloat16* __restrict__ Wb,     // [256,256] bf16, W[n][k]
    const float* __restrict__ bvec,
    const __hip_bfloat16* __restrict__ embb,
    const int* __restrict__ seg_start,
    const int* __restrict__ seg_end,
    const int* __restrict__ edge_tok,
    int M)
{
    extern __shared__ char smem[];
    __hip_bfloat16* lds = (__hip_bfloat16*)smem;   // 64KB = 64 frag groups
    const int t    = threadIdx.x;
    const int lane = t & 63;
    const int wid  = t >> 6;
    const int quad = lane >> 4;
    const int l16  = lane & 15;
    const int m0   = blockIdx.x * 128 + wid * 32;

    f32x4 acc[2][16];
#pragma unroll
    for (int mt = 0; mt < 2; ++mt)
#pragma unroll
        for (int nt = 0; nt < 16; ++nt) acc[mt][nt] = (f32x4){0.f,0.f,0.f,0.f};

    const __hip_bfloat16* arow0 = childft + (size_t)min(m0 + l16, M-1) * DD + quad * 8;
    const __hip_bfloat16* arow1 = childft + (size_t)min(m0 + 16 + l16, M-1) * DD + quad * 8;

    for (int phase = 0; phase < 2; ++phase) {
        // hoist this phase's A-fragments (global, overlaps barrier+staging)
        bf16x8 a0[4], a1[4];
#pragma unroll
        for (int k0l = 0; k0l < 4; ++k0l) {
            int k0 = phase * 128 + k0l * 32;
            a0[k0l] = *(const bf16x8*)(arow0 + k0);
            a1[k0l] = *(const bf16x8*)(arow1 + k0);
        }
        if (phase) __syncthreads();        // all waves done reading prev frags
        // stage 64KB of W in fragment order
#pragma unroll 4
        for (int it = 0; it < 16; ++it) {
            int idx = it * 256 + t;
            int g = idx >> 6, s = idx & 63;
            int nt = g & 15, k0l = g >> 4;
            int row = nt * 16 + (s & 15);
            int col = phase * 128 + k0l * 32 + (s >> 4) * 8;
            *(bf16x8*)(lds + g * 512 + s * 8) =
                *(const bf16x8*)(Wb + (size_t)row * DD + col);
        }
        __syncthreads();
#pragma unroll
        for (int k0l = 0; k0l < 4; ++k0l) {
#pragma unroll
            for (int nt = 0; nt < 16; ++nt) {
                bf16x8 b = *(const bf16x8*)(lds + (k0l * 16 + nt) * 512 + lane * 8);
                acc[0][nt] = __builtin_amdgcn_mfma_f32_16x16x32_bf16(a0[k0l], b, acc[0][nt], 0, 0, 0);
                acc[1][nt] = __builtin_amdgcn_mfma_f32_16x16x32_bf16(a1[k0l], b, acc[1][nt], 0, 0, 0);
            }
        }
    }

    float bias[16];
#pragma unroll
    for (int nt = 0; nt < 16; ++nt) bias[nt] = bvec[nt * 16 + l16];

#pragma unroll
    for (int mt = 0; mt < 2; ++mt) {
#pragma unroll
        for (int r = 0; r < 4; ++r) {
            int m = m0 + mt * 16 + quad * 4 + r;
            if (m < M) {
                int le = seg_end[m];
                bool multi = (le - seg_start[m]) > 1;
                int tok = edge_tok[le - 1];
                const __hip_bfloat16* lrow = embb + (size_t)tok * DD;
#pragma unroll
                for (int nt = 0; nt < 16; ++nt) {
                    int c = nt * 16 + l16;
                    float last = __bfloat162float(lrow[c]);
                    float v = multi ? fmaxf(acc[mt][nt][r] + bias[nt], 0.f) : 0.f;
                    childft[(size_t)m * DD + c] = __float2bfloat16(last + v);
                }
            }
        }
    }
}

// ---------------------------------------------------------------------------
// Kernel 5: classifier GEMM, same structure; Wc (128 padded rows) = one
// 64KB fragment-ordered staging; all 8 A-frags hoisted.
// ---------------------------------------------------------------------------
__global__ __launch_bounds__(256, 2) void cls_mfma(
    const __hip_bfloat16* __restrict__ ftb,    // [M,256]
    const __hip_bfloat16* __restrict__ Wcb,    // [128,256] (padded)
    const float* __restrict__ bc,
    float* __restrict__ out,                   // [M,104]
    int M)
{
    extern __shared__ char smem[];
    __hip_bfloat16* lds = (__hip_bfloat16*)smem;   // 64KB: g = k0t*8+nt
    const int t    = threadIdx.x;
    const int lane = t & 63;
    const int wid  = t >> 6;
    const int quad = lane >> 4;
    const int l16  = lane & 15;
    const int m0   = blockIdx.x * 128 + wid * 32;

    f32x4 acc[2][8];
#pragma unroll
    for (int mt = 0; mt < 2; ++mt)
#pragma unroll
        for (int nt = 0; nt < 8; ++nt) acc[mt][nt] = (f32x4){0.f,0.f,0.f,0.f};

    const __hip_bfloat16* arow0 = ftb + (size_t)min(m0 + l16, M-1) * DD + quad * 8;
    const __hip_bfloat16* arow1 = ftb + (size_t)min(m0 + 16 + l16, M-1) * DD + quad * 8;

    bf16x8 a0[8], a1[8];
#pragma unroll
    for (int k0t = 0; k0t < 8; ++k0t) {
        a0[k0t] = *(const bf16x8*)(arow0 + k0t * 32);
        a1[k0t] = *(const bf16x8*)(arow1 + k0t * 32);
    }

#pragma unroll 4
    for (int it = 0; it < 16; ++it) {
        int idx = it * 256 + t;
        int g = idx >> 6, s = idx & 63;
        int nt = g & 7, k0t = g >> 3;
        int row = nt * 16 + (s & 15);
        int col = k0t * 32 + (s >> 4) * 8;
        *(bf16x8*)(lds + g * 512 + s * 8) =
            *(const bf16x8*)(Wcb + (size_t)row * DD + col);
    }
    __syncthreads();

#pragma unroll
    for (int k0t = 0; k0t < 8; ++k0t) {
#pragma unroll
        for (int nt = 0; nt < 8; ++nt) {
            bf16x8 b = *(const bf16x8*)(lds + (k0t * 8 + nt) * 512 + lane * 8);
            acc[0][nt] = __builtin_amdgcn_mfma_f32_16x16x32_bf16(a0[k0t], b, acc[0][nt], 0, 0, 0);
            acc[1][nt] = __builtin_amdgcn_mfma_f32_16x16x32_bf16(a1[k0t], b, acc[1][nt], 0, 0, 0);
        }
    }

    float bias[8];
#pragma unroll
    for (int nt = 0; nt < 8; ++nt) {
        int c = nt * 16 + l16;
        bias[nt] = (c < CC) ? bc[c] : 0.f;
    }

#pragma unroll
    for (int mt = 0; mt < 2; ++mt) {
#pragma unroll
        for (int r = 0; r < 4; ++r) {
            int m = m0 + mt * 16 + quad * 4 + r;
            if (m < M) {
#pragma unroll
                for (int nt = 0; nt < 8; ++nt) {
                    int c = nt * 16 + l16;
                    if (c < CC)
                        out[(size_t)m * CC + c] = acc[mt][nt][r] + bias[nt];
                }
            }
        }
    }
}

// ---------------------------------------------------------------------------
extern "C" void kernel_launch(void* const* d_in, const int* in_sizes, int n_in,
                              void* d_out, int out_size, void* d_ws, size_t ws_size,
                              hipStream_t stream)
{
    const float* emb      = (const float*)d_in[0];
    const float* W        = (const float*)d_in[1];
    const float* bvec     = (const float*)d_in[2];
    const float* Wc       = (const float*)d_in[3];
    const float* bc       = (const float*)d_in[4];
    const int*   token_id = (const int*)d_in[5];
    const int*   src_idx  = (const int*)d_in[6];
    const int*   dst_idx  = (const int*)d_in[7];
    float*       out      = (float*)d_out;

    const int E     = in_sizes[6];
    const int Vemb  = in_sizes[0] / DD;
    const int n_dst = out_size / CC;
    (void)n_in; (void)ws_size;

    char* ws = (char*)d_ws;
    size_t off = 0;
    auto alloc = [&](size_t bytes) {
        void* p = ws + off;
        off = (off + bytes + 255) & ~(size_t)255;
        return p;
    };
    int* seg_start = (int*)alloc((size_t)n_dst * sizeof(int));
    int* seg_end   = (int*)alloc((size_t)n_dst * sizeof(int));
    int* edge_tok  = (int*)alloc((size_t)E * sizeof(int));
    __hip_bfloat16* childb = (__hip_bfloat16*)alloc((size_t)n_dst * DD * 2); // also ft
    __hip_bfloat16* embb   = (__hip_bfloat16*)alloc((size_t)Vemb * DD * 2);
    __hip_bfloat16* Wb     = (__hip_bfloat16*)alloc((size_t)DD * DD * 2);
    __hip_bfloat16* Wcb    = (__hip_bfloat16*)alloc((size_t)128 * DD * 2);

    const int nE4 = Vemb * (DD / 4);
    const int cvt_total = nE4 + DD * DD / 4 + 128 * DD / 4;
    const int gemm_blocks = (n_dst + 127) / 128;

    prep_kernel<<<(E + 255) / 256, 256, 0, stream>>>(
        token_id, src_idx, dst_idx, seg_start, seg_end, edge_tok, E);
    convert_kernel<<<(cvt_total + 255) / 256, 256, 0, stream>>>(
        emb, W, Wc, embb, Wb, Wcb, nE4);
    seg_sum_kernel<<<(n_dst + 3) / 4, 256, 0, stream>>>(
        embb, edge_tok, seg_start, seg_end, childb, n_dst);
    rnn_mfma<<<gemm_blocks, 256, 65536, stream>>>(
        childb, Wb, bvec, embb, seg_start, seg_end, edge_tok, n_dst);
    cls_mfma<<<gemm_blocks, 256, 65536, stream>>>(
        childb, Wcb, bc, out, n_dst);
}

// Round 5
// 206.956 us; speedup vs baseline: 3.9411x; 1.0726x over previous
//
#include <hip/hip_runtime.h>
#include <hip/hip_bf16.h>

#define DD 256
#define CC 104

typedef __bf16 bf16x8 __attribute__((ext_vector_type(8)));
typedef float  f32x4  __attribute__((ext_vector_type(4)));

__device__ inline unsigned short f2bu(float f) {
    __hip_bfloat16 h = __float2bfloat16(f);
    return *reinterpret_cast<unsigned short*>(&h);
}
__device__ inline float b2f(__hip_bfloat16 h) { return __bfloat162float(h); }

// ---------------------------------------------------------------------------
// Kernel 1: per-edge prep — edge token gather + segment boundaries
// ---------------------------------------------------------------------------
__global__ void prep_kernel(const int* __restrict__ token_id,
                            const int* __restrict__ src_idx,
                            const int* __restrict__ dst_idx,
                            int* __restrict__ seg_start,
                            int* __restrict__ seg_end,
                            int* __restrict__ edge_tok,
                            int E)
{
    int e = blockIdx.x * blockDim.x + threadIdx.x;
    if (e >= E) return;
    int d = dst_idx[e];
    edge_tok[e] = token_id[src_idx[e]];
    if (e == 0 || dst_idx[e - 1] != d) seg_start[d] = e;
    if (e == E - 1 || dst_idx[e + 1] != d) seg_end[d] = e + 1;
}

// ---------------------------------------------------------------------------
// Kernel 2: fp32 -> bf16 conversion of emb, W, and Wc (Wc zero-padded to 128)
// ---------------------------------------------------------------------------
__global__ void convert_kernel(const float* __restrict__ emb,
                               const float* __restrict__ W,
                               const float* __restrict__ Wc,
                               __hip_bfloat16* __restrict__ embb,
                               __hip_bfloat16* __restrict__ Wb,
                               __hip_bfloat16* __restrict__ Wcb,
                               int nE4)
{
    const int nW4  = DD * DD / 4;
    const int nWc4 = 128 * DD / 4;
    int i = blockIdx.x * blockDim.x + threadIdx.x;
    float4 v;
    __hip_bfloat16* dst;
    if (i < nE4) {
        v = ((const float4*)emb)[i];
        dst = embb + (size_t)i * 4;
    } else if (i < nE4 + nW4) {
        int j = i - nE4;
        v = ((const float4*)W)[j];
        dst = Wb + (size_t)j * 4;
    } else if (i < nE4 + nW4 + nWc4) {
        int j = i - nE4 - nW4;
        v = (j < CC * DD / 4) ? ((const float4*)Wc)[j]
                              : make_float4(0.f, 0.f, 0.f, 0.f);
        dst = Wcb + (size_t)j * 4;
    } else return;
    ushort4 o;
    o.x = f2bu(v.x); o.y = f2bu(v.y); o.z = f2bu(v.z); o.w = f2bu(v.w);
    *(ushort4*)dst = o;
}

// ---------------------------------------------------------------------------
// Kernel 3: segment sum (one wave per dst, half-wave per edge, 16B lanes)
// ---------------------------------------------------------------------------
__global__ void seg_sum_kernel(const __hip_bfloat16* __restrict__ embb,
                               const int* __restrict__ edge_tok,
                               const int* __restrict__ seg_start,
                               const int* __restrict__ seg_end,
                               __hip_bfloat16* __restrict__ childb,
                               int n_dst)
{
    int w = (blockIdx.x * blockDim.x + threadIdx.x) >> 6;
    int lane = threadIdx.x & 63;
    if (w >= n_dst) return;
    int h   = lane >> 5;
    int l32 = lane & 31;
    int s = seg_start[w];
    int e = seg_end[w] - 1;          // exclude last edge (RNN current input)
    float acc[8] = {0.f,0.f,0.f,0.f,0.f,0.f,0.f,0.f};

    auto accum = [&](int tok) {
        uint4 u = *(const uint4*)(embb + (size_t)tok * DD + l32 * 8);
        const unsigned* ud = (const unsigned*)&u;
#pragma unroll
        for (int d = 0; d < 4; ++d) {
            acc[2*d]   += __uint_as_float(ud[d] << 16);
            acc[2*d+1] += __uint_as_float(ud[d] & 0xffff0000u);
        }
    };

    int i = s + h;
    for (; i + 2 < e; i += 4) {
        int t0 = edge_tok[i];
        int t1 = edge_tok[i + 2];
        uint4 u0 = *(const uint4*)(embb + (size_t)t0 * DD + l32 * 8);
        uint4 u1 = *(const uint4*)(embb + (size_t)t1 * DD + l32 * 8);
        const unsigned* a0 = (const unsigned*)&u0;
        const unsigned* a1 = (const unsigned*)&u1;
#pragma unroll
        for (int d = 0; d < 4; ++d) {
            acc[2*d]   += __uint_as_float(a0[d] << 16) + __uint_as_float(a1[d] << 16);
            acc[2*d+1] += __uint_as_float(a0[d] & 0xffff0000u) + __uint_as_float(a1[d] & 0xffff0000u);
        }
    }
    if (i < e) accum(edge_tok[i]);

#pragma unroll
    for (int j = 0; j < 8; ++j) acc[j] += __shfl_xor(acc[j], 32, 64);

    if (h == 0) {
        uint4 o;
        unsigned* od = (unsigned*)&o;
#pragma unroll
        for (int d = 0; d < 4; ++d)
            od[d] = (unsigned)f2bu(acc[2*d]) | ((unsigned)f2bu(acc[2*d+1]) << 16);
        *(uint4*)(childb + (size_t)w * DD + l32 * 8) = o;
    }
}

// ---------------------------------------------------------------------------
// Kernel 4: FUSED rnn + cls.  Block = 4 waves x 64 rows (wave = one 16-row
// m-tile). ft never hits global memory.
//   1) preload 8 child A-frags + per-row seg metadata
//   2) 4 phases: stage 32KB of W (fragment order) -> 32 MFMA/wave
//   3) relu part written to LDS in C-layout (b16, LDS-only scatter)
//   4) read back in A-layout (b128) + add last_msg row-frags (8x16B gather)
//   5) 2 phases: stage 32KB of Wc -> 32 MFMA/wave; store fp32 out
//   LDS = max(32KB stage, 64x264 bf16 ft) = 33792B, reused across steps.
// ---------------------------------------------------------------------------
#define FT_STRIDE 264   // 528B rows: b128-aligned, low-conflict transpose
__global__ __launch_bounds__(256, 3) void rnn_cls_mfma(
    const __hip_bfloat16* __restrict__ childb, // [M,256] child sums
    const __hip_bfloat16* __restrict__ Wb,     // [256,256] bf16 W[n][k]
    const float* __restrict__ bvec,            // [256]
    const __hip_bfloat16* __restrict__ Wcb,    // [128,256] bf16 (padded)
    const float* __restrict__ bc,              // [104]
    const __hip_bfloat16* __restrict__ embb,   // [V,256] bf16
    const int* __restrict__ seg_start,
    const int* __restrict__ seg_end,
    const int* __restrict__ edge_tok,
    float* __restrict__ out,                   // [M,104]
    int M)
{
    extern __shared__ char smem[];
    __hip_bfloat16* lds = (__hip_bfloat16*)smem;
    const int t    = threadIdx.x;
    const int lane = t & 63;
    const int wid  = t >> 6;
    const int quad = lane >> 4;
    const int l16  = lane & 15;
    const int m0   = blockIdx.x * 64;          // block's first row
    const int mw   = m0 + wid * 16;            // wave's first row

    // --- per-row metadata (issue early; overlaps staging) ---
    // C-layout rows handled by this lane: mw + quad*4 + r
    bool multi[4];
#pragma unroll
    for (int r = 0; r < 4; ++r) {
        int m = min(mw + quad * 4 + r, M - 1);
        multi[r] = (seg_end[m] - seg_start[m]) > 1;
    }
    // A-layout row for this lane: mw + l16 -> token of its last edge
    int mrow = min(mw + l16, M - 1);
    int ltok = edge_tok[seg_end[mrow] - 1];

    // --- preload child A-frags (8 x 16B) ---
    const __hip_bfloat16* arow = childb + (size_t)mrow * DD + quad * 8;
    bf16x8 afrag[8];
#pragma unroll
    for (int k = 0; k < 8; ++k)
        afrag[k] = *(const bf16x8*)(arow + k * 32);

    float bias[16];
#pragma unroll
    for (int nt = 0; nt < 16; ++nt) bias[nt] = bvec[nt * 16 + l16];

    // --- rnn GEMM: 4 phases of K=64, W staged 32KB in fragment order ---
    f32x4 acc[16];
#pragma unroll
    for (int nt = 0; nt < 16; ++nt) acc[nt] = (f32x4){0.f,0.f,0.f,0.f};

    for (int p = 0; p < 4; ++p) {
        __syncthreads();
        // stage 32 groups (k0l_loc in [0,2), nt in [0,16)) of 1KB
#pragma unroll
        for (int it = 0; it < 8; ++it) {
            int idx = it * 256 + t;
            int g = idx >> 6, s = idx & 63;
            int nt = g & 15, kl = g >> 4;
            int row = nt * 16 + (s & 15);
            int col = (p * 2 + kl) * 32 + (s >> 4) * 8;
            *(bf16x8*)(lds + g * 512 + s * 8) =
                *(const bf16x8*)(Wb + (size_t)row * DD + col);
        }
        __syncthreads();
#pragma unroll
        for (int kl = 0; kl < 2; ++kl) {
            bf16x8 a = afrag[p * 2 + kl];
#pragma unroll
            for (int nt = 0; nt < 16; ++nt) {
                bf16x8 b = *(const bf16x8*)(lds + (kl * 16 + nt) * 512 + lane * 8);
                acc[nt] = __builtin_amdgcn_mfma_f32_16x16x32_bf16(a, b, acc[nt], 0, 0, 0);
            }
        }
    }

    // --- rnn epilogue -> LDS transpose (C-layout scatter, LDS-only) ---
    __syncthreads();    // staging buffer -> ft buffer reuse
#pragma unroll
    for (int nt = 0; nt < 16; ++nt) {
#pragma unroll
        for (int r = 0; r < 4; ++r) {
            float v = multi[r] ? fmaxf(acc[nt][r] + bias[nt], 0.f) : 0.f;
            lds[(wid * 16 + quad * 4 + r) * FT_STRIDE + nt * 16 + l16] =
                __float2bfloat16(v);
        }
    }
    __syncthreads();

    // --- read ft in A-layout + add last_msg row-fragments ---
    const __hip_bfloat16* lrow = embb + (size_t)ltok * DD + quad * 8;
    bf16x8 ftfrag[8];
#pragma unroll
    for (int k = 0; k < 8; ++k) {
        bf16x8 rp = *(const bf16x8*)(lds + (wid * 16 + l16) * FT_STRIDE + k * 32 + quad * 8);
        bf16x8 lm = *(const bf16x8*)(lrow + k * 32);
        bf16x8 o;
#pragma unroll
        for (int j = 0; j < 8; ++j)
            o[j] = (__bf16)(__bf16)((float)rp[j] + (float)lm[j]);
        ftfrag[k] = o;
    }

    // --- cls GEMM: 2 phases of K=128, Wc staged 32KB in fragment order ---
    f32x4 acc2[8];
#pragma unroll
    for (int nt = 0; nt < 8; ++nt) acc2[nt] = (f32x4){0.f,0.f,0.f,0.f};

    for (int p = 0; p < 2; ++p) {
        __syncthreads();
#pragma unroll
        for (int it = 0; it < 8; ++it) {
            int idx = it * 256 + t;
            int g = idx >> 6, s = idx & 63;   // g: kt_loc*8 + nt
            int nt = g & 7, kt = g >> 3;
            int row = nt * 16 + (s & 15);
            int col = (p * 4 + kt) * 32 + (s >> 4) * 8;
            *(bf16x8*)(lds + g * 512 + s * 8) =
                *(const bf16x8*)(Wcb + (size_t)row * DD + col);
        }
        __syncthreads();
#pragma unroll
        for (int kt = 0; kt < 4; ++kt) {
            bf16x8 a = ftfrag[p * 4 + kt];
#pragma unroll
            for (int nt = 0; nt < 8; ++nt) {
                bf16x8 b = *(const bf16x8*)(lds + (kt * 8 + nt) * 512 + lane * 8);
                acc2[nt] = __builtin_amdgcn_mfma_f32_16x16x32_bf16(a, b, acc2[nt], 0, 0, 0);
            }
        }
    }

    // --- cls epilogue: bias + fp32 store (C-layout) ---
    float bcv[8];
#pragma unroll
    for (int nt = 0; nt < 8; ++nt) {
        int c = nt * 16 + l16;
        bcv[nt] = (c < CC) ? bc[c] : 0.f;
    }
#pragma unroll
    for (int r = 0; r < 4; ++r) {
        int m = mw + quad * 4 + r;
        if (m < M) {
#pragma unroll
            for (int nt = 0; nt < 8; ++nt) {
                int c = nt * 16 + l16;
                if (c < CC)
                    out[(size_t)m * CC + c] = acc2[nt][r] + bcv[nt];
            }
        }
    }
}

// ---------------------------------------------------------------------------
extern "C" void kernel_launch(void* const* d_in, const int* in_sizes, int n_in,
                              void* d_out, int out_size, void* d_ws, size_t ws_size,
                              hipStream_t stream)
{
    const float* emb      = (const float*)d_in[0];
    const float* W        = (const float*)d_in[1];
    const float* bvec     = (const float*)d_in[2];
    const float* Wc       = (const float*)d_in[3];
    const float* bc       = (const float*)d_in[4];
    const int*   token_id = (const int*)d_in[5];
    const int*   src_idx  = (const int*)d_in[6];
    const int*   dst_idx  = (const int*)d_in[7];
    float*       out      = (float*)d_out;

    const int E     = in_sizes[6];
    const int Vemb  = in_sizes[0] / DD;
    const int n_dst = out_size / CC;
    (void)n_in; (void)ws_size;

    char* ws = (char*)d_ws;
    size_t off = 0;
    auto alloc = [&](size_t bytes) {
        void* p = ws + off;
        off = (off + bytes + 255) & ~(size_t)255;
        return p;
    };
    int* seg_start = (int*)alloc((size_t)n_dst * sizeof(int));
    int* seg_end   = (int*)alloc((size_t)n_dst * sizeof(int));
    int* edge_tok  = (int*)alloc((size_t)E * sizeof(int));
    __hip_bfloat16* childb = (__hip_bfloat16*)alloc((size_t)n_dst * DD * 2);
    __hip_bfloat16* embb   = (__hip_bfloat16*)alloc((size_t)Vemb * DD * 2);
    __hip_bfloat16* Wb     = (__hip_bfloat16*)alloc((size_t)DD * DD * 2);
    __hip_bfloat16* Wcb    = (__hip_bfloat16*)alloc((size_t)128 * DD * 2);

    const int nE4 = Vemb * (DD / 4);
    const int cvt_total = nE4 + DD * DD / 4 + 128 * DD / 4;
    const int fused_blocks = (n_dst + 63) / 64;
    const int lds_bytes = 64 * FT_STRIDE * 2;   // 33792 >= 32KB stage buffer

    prep_kernel<<<(E + 255) / 256, 256, 0, stream>>>(
        token_id, src_idx, dst_idx, seg_start, seg_end, edge_tok, E);
    convert_kernel<<<(cvt_total + 255) / 256, 256, 0, stream>>>(
        emb, W, Wc, embb, Wb, Wcb, nE4);
    seg_sum_kernel<<<(n_dst + 3) / 4, 256, 0, stream>>>(
        embb, edge_tok, seg_start, seg_end, childb, n_dst);
    rnn_cls_mfma<<<fused_blocks, 256, lds_bytes, stream>>>(
        childb, Wb, bvec, Wcb, bc, embb, seg_start, seg_end, edge_tok,
        out, n_dst);
}

// Round 6
// 199.729 us; speedup vs baseline: 4.0838x; 1.0362x over previous
//
#include <hip/hip_runtime.h>
#include <hip/hip_bf16.h>

#define DD 256
#define CC 104

typedef __bf16 bf16x8 __attribute__((ext_vector_type(8)));
typedef float  f32x4  __attribute__((ext_vector_type(4)));

__device__ inline float bu2f(unsigned short u) {
    return __uint_as_float(((unsigned)u) << 16);
}
__device__ inline unsigned short f2bu(float f) {
    __hip_bfloat16 h = __float2bfloat16(f);
    return *reinterpret_cast<unsigned short*>(&h);
}

// ---------------------------------------------------------------------------
// Kernel 1: merged prep (edge tokens + segment bounds) and fp32->bf16 convert
// of emb, W, Wc (Wc zero-padded to 128 rows). Independent work, one launch.
// ---------------------------------------------------------------------------
__global__ void prep_convert_kernel(
    const int* __restrict__ token_id,
    const int* __restrict__ src_idx,
    const int* __restrict__ dst_idx,
    int* __restrict__ seg_start,
    int* __restrict__ seg_end,
    int* __restrict__ edge_tok,
    int E, int prep_blocks,
    const float* __restrict__ emb,
    const float* __restrict__ W,
    const float* __restrict__ Wc,
    __hip_bfloat16* __restrict__ embb,
    __hip_bfloat16* __restrict__ Wb,
    __hip_bfloat16* __restrict__ Wcb,
    int nE4)
{
    if ((int)blockIdx.x < prep_blocks) {
        int e = blockIdx.x * blockDim.x + threadIdx.x;
        if (e >= E) return;
        int d = dst_idx[e];
        edge_tok[e] = token_id[src_idx[e]];
        if (e == 0 || dst_idx[e - 1] != d) seg_start[d] = e;
        if (e == E - 1 || dst_idx[e + 1] != d) seg_end[d] = e + 1;
        return;
    }
    const int nW4  = DD * DD / 4;
    const int nWc4 = 128 * DD / 4;
    int i = (blockIdx.x - prep_blocks) * blockDim.x + threadIdx.x;
    float4 v;
    __hip_bfloat16* dst;
    if (i < nE4) {
        v = ((const float4*)emb)[i];
        dst = embb + (size_t)i * 4;
    } else if (i < nE4 + nW4) {
        int j = i - nE4;
        v = ((const float4*)W)[j];
        dst = Wb + (size_t)j * 4;
    } else if (i < nE4 + nW4 + nWc4) {
        int j = i - nE4 - nW4;
        v = (j < CC * DD / 4) ? ((const float4*)Wc)[j]
                              : make_float4(0.f, 0.f, 0.f, 0.f);
        dst = Wcb + (size_t)j * 4;
    } else return;
    ushort4 o;
    o.x = f2bu(v.x); o.y = f2bu(v.y); o.z = f2bu(v.z); o.w = f2bu(v.w);
    *(ushort4*)dst = o;
}

// ---------------------------------------------------------------------------
// Kernel 2: segment sum (one wave per dst, half-wave per edge, 16B lanes)
// ---------------------------------------------------------------------------
__global__ void seg_sum_kernel(const __hip_bfloat16* __restrict__ embb,
                               const int* __restrict__ edge_tok,
                               const int* __restrict__ seg_start,
                               const int* __restrict__ seg_end,
                               __hip_bfloat16* __restrict__ childb,
                               int n_dst)
{
    int w = (blockIdx.x * blockDim.x + threadIdx.x) >> 6;
    int lane = threadIdx.x & 63;
    if (w >= n_dst) return;
    int h   = lane >> 5;
    int l32 = lane & 31;
    int s = seg_start[w];
    int e = seg_end[w] - 1;          // exclude last edge (RNN current input)
    float acc[8] = {0.f,0.f,0.f,0.f,0.f,0.f,0.f,0.f};

    auto accum = [&](int tok) {
        uint4 u = *(const uint4*)(embb + (size_t)tok * DD + l32 * 8);
        const unsigned* ud = (const unsigned*)&u;
#pragma unroll
        for (int d = 0; d < 4; ++d) {
            acc[2*d]   += __uint_as_float(ud[d] << 16);
            acc[2*d+1] += __uint_as_float(ud[d] & 0xffff0000u);
        }
    };

    int i = s + h;
    for (; i + 2 < e; i += 4) {
        int t0 = edge_tok[i];
        int t1 = edge_tok[i + 2];
        uint4 u0 = *(const uint4*)(embb + (size_t)t0 * DD + l32 * 8);
        uint4 u1 = *(const uint4*)(embb + (size_t)t1 * DD + l32 * 8);
        const unsigned* a0 = (const unsigned*)&u0;
        const unsigned* a1 = (const unsigned*)&u1;
#pragma unroll
        for (int d = 0; d < 4; ++d) {
            acc[2*d]   += __uint_as_float(a0[d] << 16) + __uint_as_float(a1[d] << 16);
            acc[2*d+1] += __uint_as_float(a0[d] & 0xffff0000u) + __uint_as_float(a1[d] & 0xffff0000u);
        }
    }
    if (i < e) accum(edge_tok[i]);

#pragma unroll
    for (int j = 0; j < 8; ++j) acc[j] += __shfl_xor(acc[j], 32, 64);

    if (h == 0) {
        uint4 o;
        unsigned* od = (unsigned*)&o;
#pragma unroll
        for (int d = 0; d < 4; ++d)
            od[d] = (unsigned)f2bu(acc[2*d]) | ((unsigned)f2bu(acc[2*d+1]) << 16);
        *(uint4*)(childb + (size_t)w * DD + l32 * 8) = o;
    }
}

// ---------------------------------------------------------------------------
// Kernel 3: RNN GEMM, operand-SWAPPED MFMA:  D = W · child^T.
//   mfma(A=W_frag, B=child_frag): lane's D = ft[row m = mw+mt*16+l16]
//   [cols c = nt*16 + quad*4 + r] -> contiguous 8B/16B epilogue vectors.
//   Block: 256 thr (4 waves) x 128-row strip; wave = 2 m-tiles.
//   W staged once per block in two 64KB halves (fragment order), acc
//   persists across the two phases. 2 blocks/CU co-resident.
//   In-place: ft overwrites childb (block owns its 128 rows; reads first).
// ---------------------------------------------------------------------------
__global__ __launch_bounds__(256, 2) void rnn_mfma(
    __hip_bfloat16* childft,                   // [M,256] in: child, out: ft
    const __hip_bfloat16* __restrict__ Wb,     // [256,256] bf16 W[n][k]
    const float* __restrict__ bvec,            // [256]
    const __hip_bfloat16* __restrict__ embb,   // [V,256] bf16
    const int* __restrict__ seg_start,
    const int* __restrict__ seg_end,
    const int* __restrict__ edge_tok,
    int M)
{
    extern __shared__ char smem[];
    __hip_bfloat16* lds = (__hip_bfloat16*)smem;   // 64KB: 64 groups of 1KB
    const int t    = threadIdx.x;
    const int lane = t & 63;
    const int wid  = t >> 6;
    const int quad = lane >> 4;
    const int l16  = lane & 15;
    const int mw   = blockIdx.x * 128 + wid * 32;  // wave's first row

    // per-lane row metadata + child A-frags (row m = l16-based!)
    int  mrow[2], ltok[2];
    bool multi[2];
    bf16x8 cfrag[2][8];
#pragma unroll
    for (int mt = 0; mt < 2; ++mt) {
        mrow[mt] = min(mw + mt * 16 + l16, M - 1);
        int ls = seg_start[mrow[mt]];
        int le = seg_end[mrow[mt]];
        multi[mt] = (le - ls) > 1;
        ltok[mt]  = edge_tok[le - 1];
        const __hip_bfloat16* arow = childft + (size_t)mrow[mt] * DD + quad * 8;
#pragma unroll
        for (int k0 = 0; k0 < 8; ++k0)
            cfrag[mt][k0] = *(const bf16x8*)(arow + k0 * 32);
    }

    f32x4 acc[2][16];
#pragma unroll
    for (int mt = 0; mt < 2; ++mt)
#pragma unroll
        for (int nt = 0; nt < 16; ++nt) acc[mt][nt] = (f32x4){0.f,0.f,0.f,0.f};

    for (int p = 0; p < 2; ++p) {
        if (p) __syncthreads();
        // stage 64KB: groups g = kl*16+nt (kl local k0, nt n-tile), chunk s
#pragma unroll
        for (int it = 0; it < 16; ++it) {
            int idx = it * 256 + t;
            int g = idx >> 6, s = idx & 63;
            int nt = g & 15, kl = g >> 4;
            int row = nt * 16 + (s & 15);
            int col = (p * 4 + kl) * 32 + (s >> 4) * 8;
            *(bf16x8*)(lds + g * 512 + s * 8) =
                *(const bf16x8*)(Wb + (size_t)row * DD + col);
        }
        __syncthreads();
#pragma unroll
        for (int kl = 0; kl < 4; ++kl) {
#pragma unroll
            for (int nt = 0; nt < 16; ++nt) {
                bf16x8 wf = *(const bf16x8*)(lds + (kl * 16 + nt) * 512 + lane * 8);
                acc[0][nt] = __builtin_amdgcn_mfma_f32_16x16x32_bf16(wf, cfrag[0][p*4+kl], acc[0][nt], 0, 0, 0);
                acc[1][nt] = __builtin_amdgcn_mfma_f32_16x16x32_bf16(wf, cfrag[1][p*4+kl], acc[1][nt], 0, 0, 0);
            }
        }
    }

    // epilogue: lane owns row mrow[mt], cols nt*16+quad*4+{0..3}
#pragma unroll
    for (int mt = 0; mt < 2; ++mt) {
        int m = mw + mt * 16 + l16;
        if (m < M) {
            const __hip_bfloat16* lrow = embb + (size_t)ltok[mt] * DD;
            bool mu = multi[mt];
#pragma unroll
            for (int nt = 0; nt < 16; ++nt) {
                int c0 = nt * 16 + quad * 4;
                float4 bia = *(const float4*)(bvec + c0);
                ushort4 lm = *(const ushort4*)(lrow + c0);
                ushort4 o;
                float v0 = mu ? fmaxf(acc[mt][nt][0] + bia.x, 0.f) : 0.f;
                float v1 = mu ? fmaxf(acc[mt][nt][1] + bia.y, 0.f) : 0.f;
                float v2 = mu ? fmaxf(acc[mt][nt][2] + bia.z, 0.f) : 0.f;
                float v3 = mu ? fmaxf(acc[mt][nt][3] + bia.w, 0.f) : 0.f;
                o.x = f2bu(v0 + bu2f(lm.x));
                o.y = f2bu(v1 + bu2f(lm.y));
                o.z = f2bu(v2 + bu2f(lm.z));
                o.w = f2bu(v3 + bu2f(lm.w));
                *(ushort4*)(childft + (size_t)m * DD + c0) = o;
            }
        }
    }
}

// ---------------------------------------------------------------------------
// Kernel 4: classifier GEMM, same swapped structure. Wc (128 padded rows)
// staged once (64KB). Lane's D = out[row m=l16-based][4 consecutive cols]
// -> float4 stores (104 = 26 exact float4 chunks).
// ---------------------------------------------------------------------------
__global__ __launch_bounds__(256, 2) void cls_mfma(
    const __hip_bfloat16* __restrict__ ftb,    // [M,256] bf16 (childft)
    const __hip_bfloat16* __restrict__ Wcb,    // [128,256] bf16 (padded)
    const float* __restrict__ bc,              // [104]
    float* __restrict__ out,                   // [M,104]
    int M)
{
    extern __shared__ char smem[];
    __hip_bfloat16* lds = (__hip_bfloat16*)smem;   // 64KB: 64 groups of 1KB
    const int t    = threadIdx.x;
    const int lane = t & 63;
    const int wid  = t >> 6;
    const int quad = lane >> 4;
    const int l16  = lane & 15;
    const int mw   = blockIdx.x * 128 + wid * 32;

    int mrow[2];
    bf16x8 ffrag[2][8];
#pragma unroll
    for (int mt = 0; mt < 2; ++mt) {
        mrow[mt] = min(mw + mt * 16 + l16, M - 1);
        const __hip_bfloat16* arow = ftb + (size_t)mrow[mt] * DD + quad * 8;
#pragma unroll
        for (int k0 = 0; k0 < 8; ++k0)
            ffrag[mt][k0] = *(const bf16x8*)(arow + k0 * 32);
    }

    // stage Wc: groups g = k0*8+nt
#pragma unroll
    for (int it = 0; it < 16; ++it) {
        int idx = it * 256 + t;
        int g = idx >> 6, s = idx & 63;
        int nt = g & 7, k0 = g >> 3;
        int row = nt * 16 + (s & 15);
        int col = k0 * 32 + (s >> 4) * 8;
        *(bf16x8*)(lds + g * 512 + s * 8) =
            *(const bf16x8*)(Wcb + (size_t)row * DD + col);
    }
    __syncthreads();

    f32x4 acc[2][8];
#pragma unroll
    for (int mt = 0; mt < 2; ++mt)
#pragma unroll
        for (int nt = 0; nt < 8; ++nt) acc[mt][nt] = (f32x4){0.f,0.f,0.f,0.f};

#pragma unroll
    for (int k0 = 0; k0 < 8; ++k0) {
#pragma unroll
        for (int nt = 0; nt < 8; ++nt) {
            bf16x8 wf = *(const bf16x8*)(lds + (k0 * 8 + nt) * 512 + lane * 8);
            acc[0][nt] = __builtin_amdgcn_mfma_f32_16x16x32_bf16(wf, ffrag[0][k0], acc[0][nt], 0, 0, 0);
            acc[1][nt] = __builtin_amdgcn_mfma_f32_16x16x32_bf16(wf, ffrag[1][k0], acc[1][nt], 0, 0, 0);
        }
    }

#pragma unroll
    for (int mt = 0; mt < 2; ++mt) {
        int m = mw + mt * 16 + l16;
        if (m < M) {
#pragma unroll
            for (int nt = 0; nt < 8; ++nt) {
                int c0 = nt * 16 + quad * 4;
                if (c0 <= 100) {
                    float4 bia = *(const float4*)(bc + c0);
                    float4 o;
                    o.x = acc[mt][nt][0] + bia.x;
                    o.y = acc[mt][nt][1] + bia.y;
                    o.z = acc[mt][nt][2] + bia.z;
                    o.w = acc[mt][nt][3] + bia.w;
                    *(float4*)(out + (size_t)m * CC + c0) = o;
                }
            }
        }
    }
}

// ---------------------------------------------------------------------------
extern "C" void kernel_launch(void* const* d_in, const int* in_sizes, int n_in,
                              void* d_out, int out_size, void* d_ws, size_t ws_size,
                              hipStream_t stream)
{
    const float* emb      = (const float*)d_in[0];
    const float* W        = (const float*)d_in[1];
    const float* bvec     = (const float*)d_in[2];
    const float* Wc       = (const float*)d_in[3];
    const float* bc       = (const float*)d_in[4];
    const int*   token_id = (const int*)d_in[5];
    const int*   src_idx  = (const int*)d_in[6];
    const int*   dst_idx  = (const int*)d_in[7];
    float*       out      = (float*)d_out;

    const int E     = in_sizes[6];
    const int Vemb  = in_sizes[0] / DD;
    const int n_dst = out_size / CC;
    (void)n_in; (void)ws_size;

    char* ws = (char*)d_ws;
    size_t off = 0;
    auto alloc = [&](size_t bytes) {
        void* p = ws + off;
        off = (off + bytes + 255) & ~(size_t)255;
        return p;
    };
    int* seg_start = (int*)alloc((size_t)n_dst * sizeof(int));
    int* seg_end   = (int*)alloc((size_t)n_dst * sizeof(int));
    int* edge_tok  = (int*)alloc((size_t)E * sizeof(int));
    __hip_bfloat16* childb = (__hip_bfloat16*)alloc((size_t)n_dst * DD * 2); // also ft
    __hip_bfloat16* embb   = (__hip_bfloat16*)alloc((size_t)Vemb * DD * 2);
    __hip_bfloat16* Wb     = (__hip_bfloat16*)alloc((size_t)DD * DD * 2);
    __hip_bfloat16* Wcb    = (__hip_bfloat16*)alloc((size_t)128 * DD * 2);

    const int nE4 = Vemb * (DD / 4);
    const int cvt_total   = nE4 + DD * DD / 4 + 128 * DD / 4;
    const int prep_blocks = (E + 255) / 256;
    const int cvt_blocks  = (cvt_total + 255) / 256;
    const int gemm_blocks = (n_dst + 127) / 128;

    prep_convert_kernel<<<prep_blocks + cvt_blocks, 256, 0, stream>>>(
        token_id, src_idx, dst_idx, seg_start, seg_end, edge_tok, E,
        prep_blocks, emb, W, Wc, embb, Wb, Wcb, nE4);
    seg_sum_kernel<<<(n_dst + 3) / 4, 256, 0, stream>>>(
        embb, edge_tok, seg_start, seg_end, childb, n_dst);
    rnn_mfma<<<gemm_blocks, 256, 65536, stream>>>(
        childb, Wb, bvec, embb, seg_start, seg_end, edge_tok, n_dst);
    cls_mfma<<<gemm_blocks, 256, 65536, stream>>>(
        childb, Wcb, bc, out, n_dst);
}